// Round 8
// baseline (186.057 us; speedup 1.0000x reference)
//
#include <hip/hip_runtime.h>

// SNN forward, R7: two-kernel split, zero structural overhead.
//
// spike(h) = (h >= 2.0f)   (h/TAU >= 1 <=> h >= 2, exact in IEEE)
//
// Insight: only rows whose layer-2 mask m2 != 0 produce nonzero output --
// O(100) rows of 2.1M. So out is ~all zeros.
//   Kernel Z: grid-stride float4 zero-fill (fillBufferAligned pattern,
//             measured 6.3 TB/s on this harness's poison fills).
//   Kernel C: no LDS, no barriers. Direct x read, exact L1 (reference op
//             order -- absmax 0.0 verified R1-R6), per-wave gmax gate
//             (h2_j <= popc(m1)*max(W2): popc*gmax < 1.99 -> provably no
//             L2 fire), rare L2/L3/L4 from global (L2-hot), scatter-write
//             only m2!=0 rows. Conditional adds in ascending index order
//             are bit-exact vs the reference fma chain.

typedef float v4f __attribute__((ext_vector_type(4)));

__global__ __launch_bounds__(256) void snn_zero(float* __restrict__ out, long n4)
{
    long i = (long)blockIdx.x * 256 + threadIdx.x;
    const long stride = (long)gridDim.x * 256;
    v4f* o4 = (v4f*)out;
    const v4f z = { 0.f, 0.f, 0.f, 0.f };
    for (; i < n4; i += stride) o4[i] = z;
}

__global__ __launch_bounds__(256) void snn_compute(
    const float* __restrict__ x,
    const float* __restrict__ W1,   // [32,5]
    const float* __restrict__ W2,   // [32,32]
    const float* __restrict__ W3,   // [16,32]
    const float* __restrict__ W4,   // [10,16]
    float* __restrict__ out,        // [B,10] (pre-zeroed by snn_zero)
    long B)
{
    // ---- per-wave gmax: max positive W2 entry (16 loads + butterfly) ----
    const int lane = threadIdx.x & 63;
    float lm = 0.0f;
#pragma unroll
    for (int k = 0; k < 16; ++k) lm = fmaxf(lm, W2[lane + 64 * k]);
#pragma unroll
    for (int k = 1; k < 64; k <<= 1) lm = fmaxf(lm, __shfl_xor(lm, k, 64));
    const float gmax = lm;   // wave-uniform

    const long tid = (long)blockIdx.x * 256 + threadIdx.x;
    const long stride = (long)gridDim.x * 256;

    for (long row = tid; row < B; row += stride) {
        const float* xp = x + row * 5;
        float x0 = xp[0], x1 = xp[1], x2 = xp[2], x3 = xp[3], x4 = xp[4];

        // ---- layer 1, exact reference op order (W1 scalarizes to s_load) ----
        unsigned m = 0u;
#pragma unroll
        for (int j = 0; j < 32; ++j) {
            const float* w = W1 + j * 5;
            float h = x0 * w[0];
            h += x1 * w[1];
            h += x2 * w[2];
            h += x3 * w[3];
            h += x4 * w[4];
            if (h >= 2.0f) m |= (1u << j);
        }

        // ---- gate: h2_j <= popc(m)*gmax*(1+3eps) < 1.99 -> no L2 fire ----
        if ((float)__popc(m) * gmax >= 1.99f) {
            float h[32];
#pragma unroll
            for (int j = 0; j < 32; ++j) h[j] = 0.0f;
            unsigned mm = m;             // ascending set-bit order == ref order
            while (mm) {
                int i = __ffs(mm) - 1;
                mm &= mm - 1;
#pragma unroll
                for (int j = 0; j < 32; ++j) h[j] += W2[j * 32 + i];  // L2-hot
            }
            unsigned m2 = 0u;
#pragma unroll
            for (int j = 0; j < 32; ++j)
                if (h[j] >= 2.0f) m2 |= (1u << j);

            if (m2) {   // O(100) rows device-wide: exact layers 3+4, scatter out
                unsigned m3 = 0u;
#pragma unroll
                for (int j = 0; j < 16; ++j) {
                    float g = 0.0f;
#pragma unroll
                    for (int i = 0; i < 32; ++i)
                        if ((m2 >> i) & 1u) g += W3[j * 32 + i];
                    if (g >= 2.0f) m3 |= (1u << j);
                }
                float* op = out + row * 10;
#pragma unroll
                for (int j = 0; j < 10; ++j) {
                    float g = 0.0f;
#pragma unroll
                    for (int i = 0; i < 16; ++i)
                        if ((m3 >> i) & 1u) g += W4[j * 16 + i];
                    op[j] = (g >= 2.0f) ? 1.0f : 0.0f;
                }
            }
        }
    }
}

extern "C" void kernel_launch(void* const* d_in, const int* in_sizes, int n_in,
                              void* d_out, int out_size, void* d_ws, size_t ws_size,
                              hipStream_t stream) {
    const float* x  = (const float*)d_in[0];
    const float* W1 = (const float*)d_in[1];
    const float* W2 = (const float*)d_in[2];
    const float* W3 = (const float*)d_in[3];
    const float* W4 = (const float*)d_in[4];
    float* out = (float*)d_out;

    long B = (long)in_sizes[0] / 5;
    long n4 = B * 10 / 4;            // out floats / 4 (B*10 divisible by 4)

    // Z first (C scatter-writes must land after the zero-fill).
    snn_zero<<<2048, 256, 0, stream>>>(out, n4);
    snn_compute<<<2048, 256, 0, stream>>>(x, W1, W2, W3, W4, out, B);
}